// Round 4
// baseline (119.307 us; speedup 1.0000x reference)
//
#include <hip/hip_runtime.h>
#include <math.h>

#define C_ 100
#define K_ 8
#define D_ 64
#define B_ 2048

using f16x8 = __attribute__((ext_vector_type(8))) _Float16;
using f32x4 = __attribute__((ext_vector_type(4))) float;

// DPP-based cross-lane add within each 16-lane group.
template <int CTRL>
__device__ __forceinline__ float dpp_xadd(float x) {
    int v = __builtin_amdgcn_update_dpp(0, __float_as_int(x), CTRL, 0xf, 0xf, true);
    return x + __int_as_float(v);
}
__device__ __forceinline__ float sum16(float x) {
    x = dpp_xadd<0xB1>(x);   // quad_perm xor1
    x = dpp_xadd<0x4E>(x);   // quad_perm xor2
    x = dpp_xadd<0x141>(x);  // row_half_mirror ≡ xor4
    x = dpp_xadd<0x140>(x);  // row_mirror ≡ xor8
    return x;
}

// ---------------- kernel 1: invert unit-lower-triangular L per (c,k) ----------------
// Register-resident substitution: thread j holds column j of A in a[64]; inner loop
// reads Ls rows = wave-uniform LDS broadcast (b128). Emits B-fragments (f16),
// v = A_f16*mu, logdet. Also casts X->f16.
#define LS_S 68
#define AT_S 65
__global__ __launch_bounds__(64) void k_invert(const float* __restrict__ L_g,
                                               const float* __restrict__ rep,
                                               const float* __restrict__ loc_g,
                                               f16x8* __restrict__ ATf,
                                               _Float16* __restrict__ Xh,
                                               float* __restrict__ v_g,
                                               float* __restrict__ ld_g) {
    const int ck = blockIdx.x;
    const int j = threadIdx.x;
    __shared__ float Ls[D_][LS_S];
    __shared__ float At[D_][AT_S];
    __shared__ float mus[D_];

    for (int idx = ck * 64 + j; idx < B_ * D_; idx += C_ * K_ * 64)
        Xh[idx] = (_Float16)rep[idx];

    const float* Lsrc = L_g + (size_t)ck * D_ * D_;
#pragma unroll
    for (int t = 0; t < D_; ++t)
        Ls[t][j] = Lsrc[t * D_ + j];
    mus[j] = loc_g[ck * D_ + j];
    __syncthreads();

    {
        float ll = __logf(fabsf(Ls[j][j]));
        ll = sum16(ll);
        ll += __shfl_xor(ll, 16, 64);
        ll += __shfl_xor(ll, 32, 64);
        if (j == 0) ld_g[ck] = ll;
    }

    float a[D_];
    const float r0 = __builtin_amdgcn_rcpf(Ls[j][j]);
#pragma unroll
    for (int m = 0; m < D_; ++m) a[m] = (j == m) ? r0 : 0.f;

#pragma unroll
    for (int i = 1; i < D_; ++i) {
        float a0 = 0.f, a1 = 0.f, a2 = 0.f, a3 = 0.f;
#pragma unroll
        for (int m0 = 0; m0 + 3 < i; m0 += 4) {
            const float4 L4 = *reinterpret_cast<const float4*>(&Ls[i][m0]);
            a0 = fmaf(L4.x, a[m0 + 0], a0);
            a1 = fmaf(L4.y, a[m0 + 1], a1);
            a2 = fmaf(L4.z, a[m0 + 2], a2);
            a3 = fmaf(L4.w, a[m0 + 3], a3);
        }
#pragma unroll
        for (int m = i & ~3; m < i; ++m) a0 = fmaf(Ls[i][m], a[m], a0);
        const float acc = (a0 + a1) + (a2 + a3);
        const float nv = -acc * __builtin_amdgcn_rcpf(Ls[i][i]);
        a[i] = (j < i) ? nv : a[i];
    }

#pragma unroll
    for (int m = 0; m < D_; ++m) At[m][j] = a[m];
    __syncthreads();

    const int q8 = (j >> 4) * 8, cl = j & 15;
    float vpart[4];
#pragma unroll
    for (int dt = 0; dt < 4; ++dt) {
        vpart[dt] = 0.f;
#pragma unroll
        for (int ks = 0; ks < 2; ++ks) {
            f16x8 t;
#pragma unroll
            for (int s = 0; s < 8; ++s) {
                const _Float16 h = (_Float16)At[dt * 16 + cl][ks * 32 + q8 + s];
                t[s] = h;
                vpart[dt] = fmaf((float)h, mus[ks * 32 + q8 + s], vpart[dt]);
            }
            ATf[(size_t)ck * 512 + (dt * 2 + ks) * 64 + j] = t;
        }
        vpart[dt] += __shfl_xor(vpart[dt], 16, 64);
        vpart[dt] += __shfl_xor(vpart[dt], 32, 64);
    }
    if (j < 16) {
#pragma unroll
        for (int dt = 0; dt < 4; ++dt)
            v_g[(size_t)ck * D_ + dt * 16 + j] = vpart[dt];
    }
}

// ---------------- kernel 2: MFMA GEMM + quad + online logsumexp over K ---------------
// block: 512 thr (8 waves) = one class c x 256 b-rows; wave handles 32 b x 64 d.
// All 8 k's B-fragments (64 KB) + v (2 KB) staged in LDS once; k-loop is LDS-only.
__global__ __launch_bounds__(512, 4) void k_main(const _Float16* __restrict__ Xh,
                                                 const f16x8* __restrict__ ATf,
                                                 const float* __restrict__ v_g,
                                                 const float* __restrict__ ml,
                                                 const float* __restrict__ ld_g,
                                                 float* __restrict__ clp_g) {
    const int c = blockIdx.y;
    const int b0 = blockIdx.x * 256;
    const int tid = threadIdx.x;
    const int wave = tid >> 6;
    const int lane = tid & 63;
    const int col = lane & 15;
    const int quad = lane >> 4;
    const int bw = b0 + wave * 32;

    __shared__ f16x8 Bs[K_ * 512];    // 64 KB: [k][frag(dt*2+ks)][lane]
    __shared__ float vs_s[K_ * D_];   // 2 KB
    __shared__ float offs_s[K_];

    // stage B fragments (coalesced 16B/lane) + v + offsets
    const f16x8* Bsrc = ATf + (size_t)c * K_ * 512;
#pragma unroll
    for (int k = 0; k < K_; ++k)
        Bs[k * 512 + tid] = Bsrc[k * 512 + tid];
    vs_s[tid] = v_g[(size_t)c * K_ * D_ + tid];     // 512 == K_*D_
    if (tid < K_) {
        float vals[K_];
        float mx = -INFINITY;
#pragma unroll
        for (int k = 0; k < K_; ++k) { vals[k] = ml[c * K_ + k]; mx = fmaxf(mx, vals[k]); }
        float s = 0.f;
#pragma unroll
        for (int k = 0; k < K_; ++k) s += __expf(vals[k] - mx);
        const float lse = mx + __logf(s);
        offs_s[tid] = vals[tid] - lse - 58.8120661251f - ld_g[c * K_ + tid];
    }

    // X A-fragments (tiny, L2-resident)
    f16x8 Xf[2][2];
#pragma unroll
    for (int bt = 0; bt < 2; ++bt)
#pragma unroll
        for (int ks = 0; ks < 2; ++ks)
            Xf[bt][ks] = *reinterpret_cast<const f16x8*>(
                Xh + (size_t)(bw + bt * 16 + col) * D_ + ks * 32 + quad * 8);

    float m_run[2][4], s_run[2][4];
#pragma unroll
    for (int bt = 0; bt < 2; ++bt)
#pragma unroll
        for (int r = 0; r < 4; ++r) { m_run[bt][r] = -INFINITY; s_run[bt][r] = 0.f; }

    const f32x4 zero = {0.f, 0.f, 0.f, 0.f};
    __syncthreads();

    for (int k = 0; k < K_; ++k) {
        float vv[4];
#pragma unroll
        for (int dt = 0; dt < 4; ++dt)
            vv[dt] = vs_s[k * D_ + dt * 16 + col];
        const float offk = offs_s[k];

        f32x4 acc[2][4];
#pragma unroll
        for (int dt = 0; dt < 4; ++dt) {
            const f16x8 B0 = Bs[k * 512 + (dt * 2 + 0) * 64 + lane];
            const f16x8 B1 = Bs[k * 512 + (dt * 2 + 1) * 64 + lane];
#pragma unroll
            for (int bt = 0; bt < 2; ++bt) {
                acc[bt][dt] = __builtin_amdgcn_mfma_f32_16x16x32_f16(
                    Xf[bt][0], B0, zero, 0, 0, 0);
                acc[bt][dt] = __builtin_amdgcn_mfma_f32_16x16x32_f16(
                    Xf[bt][1], B1, acc[bt][dt], 0, 0, 0);
            }
        }

#pragma unroll
        for (int bt = 0; bt < 2; ++bt) {
            float p[4];
#pragma unroll
            for (int r = 0; r < 4; ++r) {
                float s = 0.f;
#pragma unroll
                for (int dt = 0; dt < 4; ++dt) {
                    const float z = acc[bt][dt][r] - vv[dt];
                    s = fmaf(z, z, s);
                }
                p[r] = s;
            }
#pragma unroll
            for (int r = 0; r < 4; ++r) p[r] = sum16(p[r]);
#pragma unroll
            for (int r = 0; r < 4; ++r) {
                const float lp = fmaf(-0.5f, p[r], offk);
                const float nm = fmaxf(m_run[bt][r], lp);
                s_run[bt][r] = s_run[bt][r] * __expf(m_run[bt][r] - nm) + __expf(lp - nm);
                m_run[bt][r] = nm;
            }
        }
    }

    if (col == 0) {
#pragma unroll
        for (int bt = 0; bt < 2; ++bt)
#pragma unroll
            for (int r = 0; r < 4; ++r) {
                const int b = bw + bt * 16 + quad * 4 + r;
                clp_g[(size_t)b * C_ + c] = m_run[bt][r] + __logf(s_run[bt][r]);
            }
    }
}

// ---------------- kernel 3: log_softmax over C per batch row -------------------------
__global__ __launch_bounds__(256) void k_final(const float* __restrict__ clp,
                                               float* __restrict__ out) {
    const int wave = threadIdx.x >> 6;
    const int lane = threadIdx.x & 63;
    const int b = blockIdx.x * 4 + wave;
    const float* row = clp + (size_t)b * C_;
    const float x0 = row[lane];
    const float x1 = (lane < C_ - 64) ? row[64 + lane] : -INFINITY;
    float m = fmaxf(x0, x1);
    for (int o = 32; o > 0; o >>= 1) m = fmaxf(m, __shfl_xor(m, o, 64));
    float s = __expf(x0 - m) + ((lane < C_ - 64) ? __expf(x1 - m) : 0.f);
    for (int o = 32; o > 0; o >>= 1) s += __shfl_xor(s, o, 64);
    const float L = m + __logf(s);
    out[(size_t)b * C_ + lane] = x0 - L;
    if (lane < C_ - 64) out[(size_t)b * C_ + 64 + lane] = x1 - L;
}

extern "C" void kernel_launch(void* const* d_in, const int* in_sizes, int n_in,
                              void* d_out, int out_size, void* d_ws, size_t ws_size,
                              hipStream_t stream) {
    const float* rep = (const float*)d_in[0];        // [B, D]
    const float* ml  = (const float*)d_in[1];        // [C, K]
    const float* loc = (const float*)d_in[2];        // [C, K, D]
    const float* st  = (const float*)d_in[3];        // [C, K, D, D]
    float* out = (float*)d_out;                      // [B, C]

    char* w = (char*)d_ws;
    f16x8*    ATf = (f16x8*)w;                        // 6,553,600 B
    _Float16* Xh  = (_Float16*)(w + 6553600);         // 262,144 B
    float*    v   = (float*)(w + 6815744);            // 204,800 B
    float*    ld  = (float*)(w + 7020544);            // 3,200 B
    float*    clp = (float*)(w + 7023744);            // 819,200 B

    k_invert<<<dim3(C_ * K_), dim3(64), 0, stream>>>(st, rep, loc, ATf, Xh, v, ld);
    k_main<<<dim3(B_ / 256, C_), dim3(512), 0, stream>>>(Xh, ATf, v, ml, ld, clp);
    k_final<<<dim3(B_ / 4), dim3(256), 0, stream>>>(clp, out);
}

// Round 5
// 112.440 us; speedup vs baseline: 1.0611x; 1.0611x over previous
//
#include <hip/hip_runtime.h>
#include <math.h>

#define C_ 100
#define K_ 8
#define D_ 64
#define B_ 2048

using f16x8 = __attribute__((ext_vector_type(8))) _Float16;
using f32x4 = __attribute__((ext_vector_type(4))) float;

// DPP-based cross-lane add within each 16-lane group.
template <int CTRL>
__device__ __forceinline__ float dpp_xadd(float x) {
    int v = __builtin_amdgcn_update_dpp(0, __float_as_int(x), CTRL, 0xf, 0xf, true);
    return x + __int_as_float(v);
}
__device__ __forceinline__ float sum16(float x) {
    x = dpp_xadd<0xB1>(x);   // quad_perm xor1
    x = dpp_xadd<0x4E>(x);   // quad_perm xor2
    x = dpp_xadd<0x141>(x);  // row_half_mirror ≡ xor4
    x = dpp_xadd<0x140>(x);  // row_mirror ≡ xor8
    return x;
}

// ---------------- kernel 1: invert unit-lower-triangular L per (c,k) ----------------
#define LS_S 68
#define AT_S 65
__global__ __launch_bounds__(64, 1) void k_invert(const float* __restrict__ L_g,
                                                  const float* __restrict__ rep,
                                                  const float* __restrict__ loc_g,
                                                  f16x8* __restrict__ ATf,
                                                  _Float16* __restrict__ Xh,
                                                  float* __restrict__ v_g,
                                                  float* __restrict__ ld_g) {
    const int ck = blockIdx.x;
    const int j = threadIdx.x;
    __shared__ float Ls[D_][LS_S];
    __shared__ float At[D_][AT_S];
    __shared__ float mus[D_];

    for (int idx = ck * 64 + j; idx < B_ * D_; idx += C_ * K_ * 64)
        Xh[idx] = (_Float16)rep[idx];

    const float* Lsrc = L_g + (size_t)ck * D_ * D_;
#pragma unroll
    for (int t = 0; t < D_; ++t)
        Ls[t][j] = Lsrc[t * D_ + j];
    mus[j] = loc_g[ck * D_ + j];
    __syncthreads();

    {
        float ll = __logf(fabsf(Ls[j][j]));
        ll = sum16(ll);
        ll += __shfl_xor(ll, 16, 64);
        ll += __shfl_xor(ll, 32, 64);
        if (j == 0) ld_g[ck] = ll;
    }

    float a[D_];
    const float r0 = __builtin_amdgcn_rcpf(Ls[j][j]);
#pragma unroll
    for (int m = 0; m < D_; ++m) a[m] = (j == m) ? r0 : 0.f;

#pragma unroll
    for (int i = 1; i < D_; ++i) {
        float a0 = 0.f, a1 = 0.f, a2 = 0.f, a3 = 0.f;
#pragma unroll
        for (int m0 = 0; m0 + 3 < i; m0 += 4) {
            const float4 L4 = *reinterpret_cast<const float4*>(&Ls[i][m0]);
            a0 = fmaf(L4.x, a[m0 + 0], a0);
            a1 = fmaf(L4.y, a[m0 + 1], a1);
            a2 = fmaf(L4.z, a[m0 + 2], a2);
            a3 = fmaf(L4.w, a[m0 + 3], a3);
        }
#pragma unroll
        for (int m = i & ~3; m < i; ++m) a0 = fmaf(Ls[i][m], a[m], a0);
        const float acc = (a0 + a1) + (a2 + a3);
        const float nv = -acc * __builtin_amdgcn_rcpf(Ls[i][i]);
        a[i] = (j < i) ? nv : a[i];
    }

#pragma unroll
    for (int m = 0; m < D_; ++m) At[m][j] = a[m];
    __syncthreads();

    const int q8 = (j >> 4) * 8, cl = j & 15;
    float vpart[4];
#pragma unroll
    for (int dt = 0; dt < 4; ++dt) {
        vpart[dt] = 0.f;
#pragma unroll
        for (int ks = 0; ks < 2; ++ks) {
            f16x8 t;
#pragma unroll
            for (int s = 0; s < 8; ++s) {
                const _Float16 h = (_Float16)At[dt * 16 + cl][ks * 32 + q8 + s];
                t[s] = h;
                vpart[dt] = fmaf((float)h, mus[ks * 32 + q8 + s], vpart[dt]);
            }
            ATf[(size_t)ck * 512 + (dt * 2 + ks) * 64 + j] = t;
        }
        vpart[dt] += __shfl_xor(vpart[dt], 16, 64);
        vpart[dt] += __shfl_xor(vpart[dt], 32, 64);
    }
    if (j < 16) {
#pragma unroll
        for (int dt = 0; dt < 4; ++dt)
            v_g[(size_t)ck * D_ + dt * 16 + j] = vpart[dt];
    }
}

// ---------------- kernel 2: MFMA GEMM, wave-per-component --------------------------
// block: 512 thr (8 waves) = one class c x 256 b-rows. Wave w owns component k=w:
// its B-fragments live in registers for the whole block (loaded once). X tile staged
// in LDS (xor-swizzled chunks, conflict-free). LSE done once per row after the loop.
__global__ __launch_bounds__(512, 4) void k_main(const _Float16* __restrict__ Xh,
                                                 const f16x8* __restrict__ ATf,
                                                 const float* __restrict__ v_g,
                                                 const float* __restrict__ ml,
                                                 const float* __restrict__ ld_g,
                                                 float* __restrict__ clp_g) {
    const int c = blockIdx.y;
    const int b0 = blockIdx.x * 256;
    const int tid = threadIdx.x;
    const int w = tid >> 6;        // wave = component k
    const int lane = tid & 63;
    const int col = lane & 15;
    const int quad = lane >> 4;

    __shared__ f16x8 Xs[2048];       // 32 KB, chunk pos = ((s*2+bt)*8 + q)*16 + (q^col)
    __shared__ float qk[K_][260];    // quad results, padded
    __shared__ float offs_s[K_];

    // B-fragments for this wave's component: registers, loaded once (coalesced 16B).
    const int ck = c * K_ + w;
    f16x8 Bf[8];
#pragma unroll
    for (int f = 0; f < 8; ++f)
        Bf[f] = ATf[(size_t)ck * 512 + f * 64 + lane];
    float vv[4];
#pragma unroll
    for (int dt = 0; dt < 4; ++dt)
        vv[dt] = v_g[(size_t)ck * D_ + dt * 16 + col];

    if (tid < K_) {
        float vals[K_];
        float mx = -INFINITY;
#pragma unroll
        for (int k = 0; k < K_; ++k) { vals[k] = ml[c * K_ + k]; mx = fmaxf(mx, vals[k]); }
        float s = 0.f;
#pragma unroll
        for (int k = 0; k < K_; ++k) s += __expf(vals[k] - mx);
        const float lse = mx + __logf(s);
        offs_s[tid] = vals[tid] - lse - 58.8120661251f - ld_g[c * K_ + tid];
    }

    // stage X tile: u = p*512+tid; q fastest -> fully coalesced 1KB/wave global reads;
    // xor-swizzled LDS chunk writes (conflict-free).
#pragma unroll
    for (int p = 0; p < 4; ++p) {
        const int u = p * 512 + tid;
        const int q = u & 7, row = u >> 3;
        const f16x8 val = *reinterpret_cast<const f16x8*>(
            Xh + (size_t)(b0 + row) * D_ + q * 8);
        const int s = row >> 5, bt = (row >> 4) & 1, cc = row & 15;
        Xs[((s * 2 + bt) * 8 + q) * 16 + (q ^ cc)] = val;
    }
    __syncthreads();

    const f32x4 zero = {0.f, 0.f, 0.f, 0.f};

    for (int s = 0; s < 8; ++s) {
        // X A-fragments from swizzled LDS chunks
        f16x8 Xf[2][2];
#pragma unroll
        for (int bt = 0; bt < 2; ++bt)
#pragma unroll
            for (int ks = 0; ks < 2; ++ks) {
                const int q = ks * 4 + quad;
                Xf[bt][ks] = Xs[((s * 2 + bt) * 8 + q) * 16 + (q ^ col)];
            }

        f32x4 acc[2][4];
#pragma unroll
        for (int bt = 0; bt < 2; ++bt)
#pragma unroll
            for (int dt = 0; dt < 4; ++dt) {
                acc[bt][dt] = __builtin_amdgcn_mfma_f32_16x16x32_f16(
                    Xf[bt][0], Bf[dt * 2 + 0], zero, 0, 0, 0);
                acc[bt][dt] = __builtin_amdgcn_mfma_f32_16x16x32_f16(
                    Xf[bt][1], Bf[dt * 2 + 1], acc[bt][dt], 0, 0, 0);
            }

#pragma unroll
        for (int bt = 0; bt < 2; ++bt) {
            float p[4];
#pragma unroll
            for (int r = 0; r < 4; ++r) {
                float sum = 0.f;
#pragma unroll
                for (int dt = 0; dt < 4; ++dt) {
                    const float z = acc[bt][dt][r] - vv[dt];
                    sum = fmaf(z, z, sum);
                }
                p[r] = sum;
            }
#pragma unroll
            for (int r = 0; r < 4; ++r) p[r] = sum16(p[r]);
            if (col == 0) {
                // 4 consecutive rows -> one b128 store; row0 = s*32+bt*16+quad*4
                f32x4 pv = {p[0], p[1], p[2], p[3]};
                *reinterpret_cast<f32x4*>(&qk[w][s * 32 + bt * 16 + quad * 4]) = pv;
            }
        }
    }
    __syncthreads();

    // LSE over k, one thread per row; coalesced clp[c][b] write.
    if (tid < 256) {
        float lp[K_];
        float m = -INFINITY;
#pragma unroll
        for (int k = 0; k < K_; ++k) {
            lp[k] = fmaf(-0.5f, qk[k][tid], offs_s[k]);
            m = fmaxf(m, lp[k]);
        }
        float s = 0.f;
#pragma unroll
        for (int k = 0; k < K_; ++k) s += __expf(lp[k] - m);
        clp_g[(size_t)c * B_ + b0 + tid] = m + __logf(s);
    }
}

// ---------------- kernel 3: log_softmax over C per batch row -------------------------
// clp layout is [C][B]; lane = class index (strided reads, L2/L3-resident).
__global__ __launch_bounds__(256) void k_final(const float* __restrict__ clp,
                                               float* __restrict__ out) {
    const int wave = threadIdx.x >> 6;
    const int lane = threadIdx.x & 63;
    const int b = blockIdx.x * 4 + wave;
    const float x0 = clp[(size_t)lane * B_ + b];
    const float x1 = (lane < C_ - 64) ? clp[(size_t)(64 + lane) * B_ + b] : -INFINITY;
    float m = fmaxf(x0, x1);
    for (int o = 32; o > 0; o >>= 1) m = fmaxf(m, __shfl_xor(m, o, 64));
    float s = __expf(x0 - m) + ((lane < C_ - 64) ? __expf(x1 - m) : 0.f);
    for (int o = 32; o > 0; o >>= 1) s += __shfl_xor(s, o, 64);
    const float L = m + __logf(s);
    out[(size_t)b * C_ + lane] = x0 - L;
    if (lane < C_ - 64) out[(size_t)b * C_ + 64 + lane] = x1 - L;
}

extern "C" void kernel_launch(void* const* d_in, const int* in_sizes, int n_in,
                              void* d_out, int out_size, void* d_ws, size_t ws_size,
                              hipStream_t stream) {
    const float* rep = (const float*)d_in[0];        // [B, D]
    const float* ml  = (const float*)d_in[1];        // [C, K]
    const float* loc = (const float*)d_in[2];        // [C, K, D]
    const float* st  = (const float*)d_in[3];        // [C, K, D, D]
    float* out = (float*)d_out;                      // [B, C]

    char* w = (char*)d_ws;
    f16x8*    ATf = (f16x8*)w;                        // 6,553,600 B
    _Float16* Xh  = (_Float16*)(w + 6553600);         // 262,144 B
    float*    v   = (float*)(w + 6815744);            // 204,800 B
    float*    ld  = (float*)(w + 7020544);            // 3,200 B
    float*    clp = (float*)(w + 7023744);            // 819,200 B  [C][B]

    k_invert<<<dim3(C_ * K_), dim3(64), 0, stream>>>(st, rep, loc, ATf, Xh, v, ld);
    k_main<<<dim3(B_ / 256, C_), dim3(512), 0, stream>>>(Xh, ATf, v, ml, ld, clp);
    k_final<<<dim3(B_ / 4), dim3(256), 0, stream>>>(clp, out);
}